// Round 2
// baseline (146.423 us; speedup 1.0000x reference)
//
#include <hip/hip_runtime.h>
#include <stdint.h>

#define NTOK 4096
#define CDIM 512
#define HEADS 8
#define DHEAD 64
#define PHEAD (NTOK * DHEAD)          // 262144 elems per head per tensor
#define LDS_K 72                      // padded LDS row stride for BK=64 (144 B -> 2-way banks)

typedef __bf16 bf16x8 __attribute__((ext_vector_type(8)));
typedef float f32x4 __attribute__((ext_vector_type(4)));

__device__ __forceinline__ unsigned short bfbits(float f) {
    return __builtin_bit_cast(unsigned short, (__bf16)f);   // hw v_cvt on gfx950
}

__device__ __forceinline__ f32x4 mfma32(bf16x8 a, bf16x8 b, f32x4 c) {
    return __builtin_amdgcn_mfma_f32_16x16x32_bf16(a, b, c, 0, 0, 0);
}

// cvt 8 fp32 (in regs) -> 8 bf16 into LDS
__device__ __forceinline__ void cvt_store8(unsigned short* dst, float4 v0, float4 v1) {
    ushort4 o0, o1;
    o0.x = bfbits(v0.x); o0.y = bfbits(v0.y); o0.z = bfbits(v0.z); o0.w = bfbits(v0.w);
    o1.x = bfbits(v1.x); o1.y = bfbits(v1.y); o1.z = bfbits(v1.z); o1.w = bfbits(v1.w);
    *(ushort4*)dst = o0;
    *(ushort4*)(dst + 4) = o1;
}

// ---------------- QKV GEMM: 64x128 tiles, BK=64 (8 K-steps, 16 MFMA/step) ----------------
__global__ __launch_bounds__(256) void gemm_qkv(
    const float* __restrict__ A,            // x  [4096][512] fp32
    const float* __restrict__ Bm,           // Wqkv [1536][512] fp32
    const float* __restrict__ bias,
    const float* __restrict__ scale_p,
    unsigned short* __restrict__ qkv_out)
{
    // main loop: lA 64x72 + lB 128x72 = 13824 shorts; epilogue reuses first 64*136=8704
    __shared__ __align__(16) unsigned short smem[64 * LDS_K + 128 * LDS_K];
    unsigned short* lA = smem;
    unsigned short* lB = smem + 64 * LDS_K;

    const int tid = threadIdx.x;
    const int mBase = blockIdx.y * 64, nBase = blockIdx.x * 128;
    const int lane = tid & 63;
    const int w = __builtin_amdgcn_readfirstlane(tid >> 6);
    const int l16 = lane & 15, quad = lane >> 4;

    // staging assignment: A 64x64 -> 16 f32/thread; B 128x64 -> 32 f32/thread
    const int rA = tid >> 2, cA = (tid & 3) * 16;
    const int rB = tid >> 1, cB = (tid & 1) * 32;
    const float* pA = &A[(size_t)(mBase + rA) * CDIM + cA];
    const float* pB = &Bm[(size_t)(nBase + rB) * CDIM + cB];

    f32x4 acc[4][2] = {};   // wave w owns cols [w*32, w*32+32), all 64 rows

    float4 ra[4], rb[8];
    auto issue = [&](int kt) {
#pragma unroll
        for (int u = 0; u < 4; ++u) ra[u] = *(const float4*)(pA + kt + u * 4);
#pragma unroll
        for (int u = 0; u < 8; ++u) rb[u] = *(const float4*)(pB + kt + u * 4);
    };
    issue(0);

    for (int kt = 0; kt < CDIM; kt += 64) {
        __syncthreads();
        cvt_store8(&lA[rA * LDS_K + cA], ra[0], ra[1]);
        cvt_store8(&lA[rA * LDS_K + cA + 8], ra[2], ra[3]);
        cvt_store8(&lB[rB * LDS_K + cB], rb[0], rb[1]);
        cvt_store8(&lB[rB * LDS_K + cB + 8], rb[2], rb[3]);
        cvt_store8(&lB[rB * LDS_K + cB + 16], rb[4], rb[5]);
        cvt_store8(&lB[rB * LDS_K + cB + 24], rb[6], rb[7]);
        __syncthreads();
        if (kt + 64 < CDIM) issue(kt + 64);   // loads in flight under the MFMAs

#pragma unroll
        for (int kk = 0; kk < 64; kk += 32) {
            bf16x8 af[4], bfr[2];
#pragma unroll
            for (int i = 0; i < 4; ++i)
                af[i] = *(const bf16x8*)&lA[(i * 16 + l16) * LDS_K + kk + quad * 8];
#pragma unroll
            for (int j = 0; j < 2; ++j)
                bfr[j] = *(const bf16x8*)&lB[(w * 32 + j * 16 + l16) * LDS_K + kk + quad * 8];
#pragma unroll
            for (int i = 0; i < 4; ++i)
#pragma unroll
                for (int j = 0; j < 2; ++j)
                    acc[i][j] = mfma32(af[i], bfr[j], acc[i][j]);
        }
    }

    const int three = nBase >> 9;               // block-uniform: 0 q, 1 k, 2 v
    const float scl = scale_p[0] * 1.44269504f; // fold log2(e)
    const float mul = (three == 0) ? scl : 1.0f;

    __syncthreads();
#pragma unroll
    for (int i = 0; i < 4; ++i)
#pragma unroll
        for (int j = 0; j < 2; ++j)
#pragma unroll
            for (int r = 0; r < 4; ++r) {
                const int rl = i * 16 + quad * 4 + r;
                const int cl = w * 32 + j * 16 + l16;
                const float v = (acc[i][j][r] + bias[nBase + cl]) * mul;
                smem[rl * 136 + cl] = bfbits(v);
            }
    __syncthreads();

    const size_t base3 = (size_t)three * (PHEAD * HEADS);
    if (three < 2) {
        // Q/K frag layout [h][t16][d2][quad*16+l16][8]
#pragma unroll
        for (int pass = 0; pass < 4; ++pass) {
            const int idx = pass * 256 + tid;
            const int rl16 = idx & 15, qc = (idx >> 4) & 7;
            const int hsel = (idx >> 7) & 1, t16l = (idx >> 8) & 3;
            const uint4 d = *(const uint4*)&smem[(t16l * 16 + rl16) * 136 + hsel * 64 + qc * 8];
            const int hh = ((nBase >> 6) + hsel) & 7;
            const int t16 = (mBase >> 4) + t16l;
            const size_t dst = base3 + (size_t)hh * PHEAD +
                (size_t)(((t16 * 2 + (qc >> 2)) * 64 + (qc & 3) * 16 + rl16) * 8);
            *(uint4*)&qkv_out[dst] = d;
        }
    } else {
        // V frag layout [h][k32][dt][quad*16+l16][8] (key-permuted for PV mfma32)
#pragma unroll
        for (int pass = 0; pass < 4; ++pass) {
            const int idx = pass * 256 + tid;
            const int l16t = idx & 15, quadt = (idx >> 4) & 3;
            const int dt = (idx >> 6) & 3, k32l = (idx >> 8) & 1, hsel = (idx >> 9) & 1;
            const int col = hsel * 64 + dt * 16 + l16t;
            unsigned short o8[8];
#pragma unroll
            for (int e = 0; e < 4; ++e) {
                o8[e]     = smem[(k32l * 32 + quadt * 4 + e) * 136 + col];
                o8[e + 4] = smem[(k32l * 32 + 16 + quadt * 4 + e) * 136 + col];
            }
            const int hh = ((nBase >> 6) + hsel) & 7;
            const int k32 = (mBase >> 5) + k32l;
            const size_t dst = base3 + (size_t)hh * PHEAD +
                (size_t)(((k32 * 4 + dt) * 64 + quadt * 16 + l16t) * 8);
            *(uint4*)&qkv_out[dst] = *(uint4*)o8;
        }
    }
}

// ---------------- flash attention v8: Q-tile 64, K+V双 double-buffer, VALU l-sum ------------
__global__ __launch_bounds__(256, 2) void flash8_k(
    const unsigned short* __restrict__ qf,
    const unsigned short* __restrict__ kf,
    const unsigned short* __restrict__ vf,
    unsigned short* __restrict__ attn_out)   // [N][C] bf16
{
    __shared__ float ldsO[4][64][68];   // 69632 B
    __shared__ float sml[4][64];

    const int tid = threadIdx.x;
    const int lane = tid & 63;
    const int w = __builtin_amdgcn_readfirstlane(tid >> 6);
    const int l16 = lane & 15, quad = lane >> 4;
    const int h = blockIdx.x, qb = blockIdx.y;     // XCD swizzle: x = head

    const unsigned short* qh = qf + (size_t)h * PHEAD;
    const unsigned short* kb = kf + (size_t)h * PHEAD + w * 65536;   // 1024 keys/wave
    const unsigned short* vb = vf + (size_t)h * PHEAD + w * 65536;

    bf16x8 qfr[4][2];
#pragma unroll
    for (int qt = 0; qt < 4; ++qt)
#pragma unroll
        for (int d2 = 0; d2 < 2; ++d2)
            qfr[qt][d2] = *(const bf16x8*)&qh[((qb * 4 + qt) * 2 + d2) * 512 + lane * 8];

    f32x4 oacc[4][4] = {};   // [dtile][qtile]: O^T  d=quad*4+r, q=l16
    float lv[4] = {};        // per-lane partial l (8 k-slots), quad-reduced at end

    bf16x8 kA[4], kB[4], vA[4], vB[4];
#pragma unroll
    for (int i = 0; i < 4; ++i) {
        kA[i] = *(const bf16x8*)&kb[i * 512 + lane * 8];
        vA[i] = *(const bf16x8*)&vb[i * 512 + lane * 8];
    }

    auto body = [&](int g, bf16x8* kuse, bf16x8* kload, bf16x8* vuse, bf16x8* vload) {
        const int gn = (g + 1) & 31;   // wrap: final prefetch re-reads g=0 (discarded)
#pragma unroll
        for (int i = 0; i < 4; ++i)
            kload[i] = *(const bf16x8*)&kb[gn * 2048 + i * 512 + lane * 8];
#pragma unroll
        for (int i = 0; i < 4; ++i)
            vload[i] = *(const bf16x8*)&vb[gn * 2048 + i * 512 + lane * 8];

        f32x4 s0[4], s1[4];
        __builtin_amdgcn_s_setprio(1);
#pragma unroll
        for (int qt = 0; qt < 4; ++qt) {
            f32x4 a = {};
            a = mfma32(kuse[0], qfr[qt][0], a);
            a = mfma32(kuse[1], qfr[qt][1], a);
            s0[qt] = a;
            f32x4 b = {};
            b = mfma32(kuse[2], qfr[qt][0], b);
            b = mfma32(kuse[3], qfr[qt][1], b);
            s1[qt] = b;
        }
        __builtin_amdgcn_s_setprio(0);

        bf16x8 pf[4];
#pragma unroll
        for (int qt = 0; qt < 4; ++qt) {
            float e0[4], e1[4];
#pragma unroll
            for (int r = 0; r < 4; ++r) {
                e0[r] = __builtin_amdgcn_exp2f(s0[qt][r]);
                e1[r] = __builtin_amdgcn_exp2f(s1[qt][r]);
            }
            lv[qt] += ((e0[0] + e0[1]) + (e0[2] + e0[3])) +
                      ((e1[0] + e1[1]) + (e1[2] + e1[3]));
            bf16x8 pb;
#pragma unroll
            for (int r = 0; r < 4; ++r) {
                pb[r]     = (__bf16)e0[r];
                pb[4 + r] = (__bf16)e1[r];
            }
            pf[qt] = pb;
        }

        __builtin_amdgcn_s_setprio(1);
#pragma unroll
        for (int dt = 0; dt < 4; ++dt)
#pragma unroll
            for (int qt = 0; qt < 4; ++qt)
                oacc[dt][qt] = mfma32(vuse[dt], pf[qt], oacc[dt][qt]);
        __builtin_amdgcn_s_setprio(0);
    };

    for (int it = 0; it < 16; ++it) {
        body(it * 2 + 0, kA, kB, vA, vB);
        body(it * 2 + 1, kB, kA, vB, vA);
    }

    // l: reduce lv over the 4 quads (keys are distributed quad-wise)
#pragma unroll
    for (int qt = 0; qt < 4; ++qt) {
        float L = lv[qt];
        L += __shfl_xor(L, 16, 64);
        L += __shfl_xor(L, 32, 64);
        if (quad == 0) sml[w][qt * 16 + l16] = L;
    }
#pragma unroll
    for (int qt = 0; qt < 4; ++qt) {
        const int q = qt * 16 + l16;
#pragma unroll
        for (int dt = 0; dt < 4; ++dt)
            *(f32x4*)&ldsO[w][q][dt * 16 + quad * 4] = oacc[dt][qt];
    }
    __syncthreads();
#pragma unroll
    for (int pass = 0; pass < 2; ++pass) {
        const int idx = pass * 256 + tid;
        const int q = idx >> 3, dseg = (idx & 7) * 8;
        const float L = sml[0][q] + sml[1][q] + sml[2][q] + sml[3][q];
        const float inv = 1.f / L;
        unsigned short o8[8];
#pragma unroll
        for (int i = 0; i < 8; ++i) {
            const float v = ldsO[0][q][dseg + i] + ldsO[1][q][dseg + i] +
                            ldsO[2][q][dseg + i] + ldsO[3][q][dseg + i];
            o8[i] = bfbits(v * inv);
        }
        *(uint4*)&attn_out[(size_t)(qb * 64 + q) * CDIM + h * DHEAD + dseg] = *(uint4*)o8;
    }
}

// ---------------- proj GEMM: 64x64 tiles, BK=64 (8 K-steps, 8 MFMA/step) -------------------
__global__ __launch_bounds__(256) void gemm_proj(
    const unsigned short* __restrict__ A,   // attn [4096][512] bf16
    const float* __restrict__ Bm,           // Wproj [512][512] fp32
    const float* __restrict__ bias,
    float* __restrict__ c_out)              // [4096][512] fp32
{
    __shared__ __align__(16) unsigned short smem[2 * 64 * LDS_K];  // 18432 B
    unsigned short* lA = smem;
    unsigned short* lB = smem + 64 * LDS_K;

    const int tid = threadIdx.x;
    const int mBase = blockIdx.y * 64, nBase = blockIdx.x * 64;
    const int lane = tid & 63;
    const int w = __builtin_amdgcn_readfirstlane(tid >> 6);
    const int l16 = lane & 15, quad = lane >> 4;

    const int rT = tid >> 2, cT = (tid & 3) * 16;   // both tiles: 64 rows, 16 elems/thread
    const unsigned short* pA = &A[(size_t)(mBase + rT) * CDIM + cT];
    const float* pB = &Bm[(size_t)(nBase + rT) * CDIM + cT];

    f32x4 acc[4] = {};   // wave w owns cols [w*16, w*16+16), all 64 rows

    uint4 rA0, rA1; float4 rb[4];
    auto issue = [&](int kt) {
        rA0 = *(const uint4*)(pA + kt);
        rA1 = *(const uint4*)(pA + kt + 8);
#pragma unroll
        for (int u = 0; u < 4; ++u) rb[u] = *(const float4*)(pB + kt + u * 4);
    };
    issue(0);

    for (int kt = 0; kt < CDIM; kt += 64) {
        __syncthreads();
        *(uint4*)&lA[rT * LDS_K + cT]     = rA0;
        *(uint4*)&lA[rT * LDS_K + cT + 8] = rA1;
        cvt_store8(&lB[rT * LDS_K + cT], rb[0], rb[1]);
        cvt_store8(&lB[rT * LDS_K + cT + 8], rb[2], rb[3]);
        __syncthreads();
        if (kt + 64 < CDIM) issue(kt + 64);

#pragma unroll
        for (int kk = 0; kk < 64; kk += 32) {
            bf16x8 af[4], bfr;
#pragma unroll
            for (int i = 0; i < 4; ++i)
                af[i] = *(const bf16x8*)&lA[(i * 16 + l16) * LDS_K + kk + quad * 8];
            bfr = *(const bf16x8*)&lB[(w * 16 + l16) * LDS_K + kk + quad * 8];
#pragma unroll
            for (int i = 0; i < 4; ++i)
                acc[i] = mfma32(af[i], bfr, acc[i]);
        }
    }

#pragma unroll
    for (int i = 0; i < 4; ++i)
#pragma unroll
        for (int r = 0; r < 4; ++r) {
            const int grow = mBase + i * 16 + quad * 4 + r;
            const int gcol = nBase + w * 16 + l16;
            c_out[(size_t)grow * CDIM + gcol] = acc[i][r] + bias[gcol];
        }
}

extern "C" void kernel_launch(void* const* d_in, const int* in_sizes, int n_in,
                              void* d_out, int out_size, void* d_ws, size_t ws_size,
                              hipStream_t stream) {
    const float* x       = (const float*)d_in[0];
    const float* scale_p = (const float*)d_in[3];
    const float* Wqkv    = (const float*)d_in[4];
    const float* bqkv    = (const float*)d_in[5];
    const float* Wproj   = (const float*)d_in[6];
    const float* bproj   = (const float*)d_in[7];
    float* out = (float*)d_out;

    char* ws = (char*)d_ws;
    const size_t OFF_QKV  = 0;                        // 3*8*PHEAD bf16 = 12 MB
    const size_t OFF_ATTN = 12582912;                 // 4096*512 bf16  = 4 MB
    const size_t NEEDED   = OFF_ATTN + 4194304;       // 16 MB
    if (ws_size < NEEDED) return;

    unsigned short* qkvb  = (unsigned short*)(ws + OFF_QKV);
    unsigned short* attnb = (unsigned short*)(ws + OFF_ATTN);

    gemm_qkv<<<dim3(12, 64), 256, 0, stream>>>(x, Wqkv, bqkv, scale_p, qkvb);

    const unsigned short* qfr = qkvb;
    const unsigned short* kfr = qkvb + (size_t)PHEAD * HEADS;
    const unsigned short* vfr = qkvb + (size_t)2 * PHEAD * HEADS;
    flash8_k<<<dim3(8, 64), 256, 0, stream>>>(qfr, kfr, vfr, attnb);

    gemm_proj<<<dim3(8, 64), 256, 0, stream>>>(attnb, Wproj, bproj, out);
}

// Round 3
// 131.978 us; speedup vs baseline: 1.1095x; 1.1095x over previous
//
#include <hip/hip_runtime.h>
#include <stdint.h>

#define NTOK 4096
#define CDIM 512
#define HEADS 8
#define DHEAD 64
#define PHEAD (NTOK * DHEAD)          // 262144 elems per head per tensor
#define LDS_K 40                      // padded LDS row stride (shorts): 80 B -> 2-way banks

typedef __bf16 bf16x8 __attribute__((ext_vector_type(8)));
typedef float f32x4 __attribute__((ext_vector_type(4)));

__device__ __forceinline__ unsigned short bfbits(float f) {
    return __builtin_bit_cast(unsigned short, (__bf16)f);   // hw v_cvt on gfx950
}

__device__ __forceinline__ f32x4 mfma32(bf16x8 a, bf16x8 b, f32x4 c) {
    return __builtin_amdgcn_mfma_f32_16x16x32_bf16(a, b, c, 0, 0, 0);
}

// cvt 8 fp32 (in regs) -> 8 bf16, single 16B store
__device__ __forceinline__ void cvt_store8(unsigned short* dst, float4 v0, float4 v1) {
    unsigned short o[8];
    o[0] = bfbits(v0.x); o[1] = bfbits(v0.y); o[2] = bfbits(v0.z); o[3] = bfbits(v0.w);
    o[4] = bfbits(v1.x); o[5] = bfbits(v1.y); o[6] = bfbits(v1.z); o[7] = bfbits(v1.w);
    *(uint4*)dst = *(const uint4*)o;
}

// ---------------- pre-cast: x / Wqkv / Wproj fp32 -> bf16 (one pass, ~18 MB) ----------------
__global__ __launch_bounds__(256) void cast3_k(
    const float* __restrict__ x, const float* __restrict__ wq, const float* __restrict__ wp,
    unsigned short* __restrict__ xb, unsigned short* __restrict__ wqb,
    unsigned short* __restrict__ wpb)
{
    const int b = blockIdx.x;
    const float* src; unsigned short* dst; int off;
    if (b < 1024)      { src = x;  dst = xb;  off = b; }          // 4096*512 = 1024 blk
    else if (b < 1408) { src = wq; dst = wqb; off = b - 1024; }   // 1536*512 = 384 blk
    else               { src = wp; dst = wpb; off = b - 1408; }   // 512*512  = 128 blk
    const int i = (off * 256 + threadIdx.x) * 8;
    const float4 v0 = *(const float4*)(src + i);
    const float4 v1 = *(const float4*)(src + i + 4);
    cvt_store8(dst + i, v0, v1);
}

// ---------------- QKV GEMM: 64x128 tiles (768 blocks = 3/CU), bf16-in, reg-prefetch --------
__global__ __launch_bounds__(256) void gemm_qkv(
    const unsigned short* __restrict__ A,   // x bf16 [4096][512]
    const unsigned short* __restrict__ Bm,  // Wqkv bf16 [1536][512]
    const float* __restrict__ bias,
    const float* __restrict__ scale_p,
    unsigned short* __restrict__ qkv_out)
{
    __shared__ __align__(16) unsigned short smem[64 * 136];   // 17408 B (epilogue 64x136)
    unsigned short* lA = smem;                  // 64 x LDS_K
    unsigned short* lB = smem + 64 * LDS_K;     // 128 x LDS_K

    const int tid = threadIdx.x;
    const int mBase = blockIdx.y * 64, nBase = blockIdx.x * 128;
    const int lane = tid & 63;
    const int w = __builtin_amdgcn_readfirstlane(tid >> 6);
    const int l16 = lane & 15, quad = lane >> 4;
    const int srow = tid >> 2, scol = (tid & 3) * 8;

    const unsigned short* pA  = &A[(size_t)(mBase + srow) * CDIM + scol];
    const unsigned short* pB0 = &Bm[(size_t)(nBase + srow) * CDIM + scol];
    const unsigned short* pB1 = &Bm[(size_t)(nBase + 64 + srow) * CDIM + scol];

    f32x4 acc[4][2] = {};   // wave w owns cols [w*32, w*32+32), all 64 rows

    uint4 rA, rB0, rB1;
    auto issue = [&](int kt) {
        rA  = *(const uint4*)(pA + kt);
        rB0 = *(const uint4*)(pB0 + kt);
        rB1 = *(const uint4*)(pB1 + kt);
    };
    issue(0);

    for (int kt = 0; kt < CDIM; kt += 32) {
        __syncthreads();
        *(uint4*)&lA[srow * LDS_K + scol]        = rA;
        *(uint4*)&lB[srow * LDS_K + scol]        = rB0;
        *(uint4*)&lB[(64 + srow) * LDS_K + scol] = rB1;
        __syncthreads();
        if (kt + 32 < CDIM) issue(kt + 32);   // loads in flight under the MFMAs

        bf16x8 af[4], bfr[2];
#pragma unroll
        for (int i = 0; i < 4; ++i)
            af[i] = *(const bf16x8*)&lA[(i * 16 + l16) * LDS_K + quad * 8];
#pragma unroll
        for (int j = 0; j < 2; ++j)
            bfr[j] = *(const bf16x8*)&lB[(w * 32 + j * 16 + l16) * LDS_K + quad * 8];
#pragma unroll
        for (int i = 0; i < 4; ++i)
#pragma unroll
            for (int j = 0; j < 2; ++j)
                acc[i][j] = mfma32(af[i], bfr[j], acc[i][j]);
    }

    const int three = nBase >> 9;               // block-uniform: 0 q, 1 k, 2 v
    const float scl = scale_p[0] * 1.44269504f; // fold log2(e)
    const float mul = (three == 0) ? scl : 1.0f;

    __syncthreads();
#pragma unroll
    for (int i = 0; i < 4; ++i)
#pragma unroll
        for (int j = 0; j < 2; ++j)
#pragma unroll
            for (int r = 0; r < 4; ++r) {
                const int rl = i * 16 + quad * 4 + r;
                const int cl = w * 32 + j * 16 + l16;
                const float v = (acc[i][j][r] + bias[nBase + cl]) * mul;
                smem[rl * 136 + cl] = bfbits(v);
            }
    __syncthreads();

    const size_t base3 = (size_t)three * (PHEAD * HEADS);
    if (three < 2) {
        // Q/K frag layout [h][t16][d2][quad*16+l16][8]
#pragma unroll
        for (int pass = 0; pass < 4; ++pass) {
            const int idx = pass * 256 + tid;
            const int rl16 = idx & 15, qc = (idx >> 4) & 7;
            const int hsel = (idx >> 7) & 1, t16l = (idx >> 8) & 3;
            const uint4 d = *(const uint4*)&smem[(t16l * 16 + rl16) * 136 + hsel * 64 + qc * 8];
            const int hh = ((nBase >> 6) + hsel) & 7;
            const int t16 = (mBase >> 4) + t16l;
            const size_t dst = base3 + (size_t)hh * PHEAD +
                (size_t)(((t16 * 2 + (qc >> 2)) * 64 + (qc & 3) * 16 + rl16) * 8);
            *(uint4*)&qkv_out[dst] = d;
        }
    } else {
        // V frag layout [h][k32][dt][quad*16+l16][8] (key-permuted for PV mfma32)
#pragma unroll
        for (int pass = 0; pass < 4; ++pass) {
            const int idx = pass * 256 + tid;
            const int l16t = idx & 15, quadt = (idx >> 4) & 3;
            const int dt = (idx >> 6) & 3, k32l = (idx >> 8) & 1, hsel = (idx >> 9) & 1;
            const int col = hsel * 64 + dt * 16 + l16t;
            unsigned short o8[8];
#pragma unroll
            for (int e = 0; e < 4; ++e) {
                o8[e]     = smem[(k32l * 32 + quadt * 4 + e) * 136 + col];
                o8[e + 4] = smem[(k32l * 32 + 16 + quadt * 4 + e) * 136 + col];
            }
            const int hh = ((nBase >> 6) + hsel) & 7;
            const int k32 = (mBase >> 5) + k32l;
            const size_t dst = base3 + (size_t)hh * PHEAD +
                (size_t)(((k32 * 4 + dt) * 64 + quadt * 16 + l16t) * 8);
            *(uint4*)&qkv_out[dst] = *(uint4*)o8;
        }
    }
}

// ---------------- flash attention v8: Q-tile 64, K+V double-buffer, VALU l-sum --------------
__global__ __launch_bounds__(256, 2) void flash8_k(
    const unsigned short* __restrict__ qf,
    const unsigned short* __restrict__ kf,
    const unsigned short* __restrict__ vf,
    unsigned short* __restrict__ attn_out)   // [N][C] bf16
{
    __shared__ float ldsO[4][64][68];   // 69632 B
    __shared__ float sml[4][64];

    const int tid = threadIdx.x;
    const int lane = tid & 63;
    const int w = __builtin_amdgcn_readfirstlane(tid >> 6);
    const int l16 = lane & 15, quad = lane >> 4;
    const int h = blockIdx.x, qb = blockIdx.y;     // XCD swizzle: x = head

    const unsigned short* qh = qf + (size_t)h * PHEAD;
    const unsigned short* kb = kf + (size_t)h * PHEAD + w * 65536;   // 1024 keys/wave
    const unsigned short* vb = vf + (size_t)h * PHEAD + w * 65536;

    bf16x8 qfr[4][2];
#pragma unroll
    for (int qt = 0; qt < 4; ++qt)
#pragma unroll
        for (int d2 = 0; d2 < 2; ++d2)
            qfr[qt][d2] = *(const bf16x8*)&qh[((qb * 4 + qt) * 2 + d2) * 512 + lane * 8];

    f32x4 oacc[4][4] = {};   // [dtile][qtile]: O^T  d=quad*4+r, q=l16
    float lv[4] = {};        // per-lane partial l, quad-reduced at end

    bf16x8 kA[4], kB[4], vA[4], vB[4];
#pragma unroll
    for (int i = 0; i < 4; ++i) {
        kA[i] = *(const bf16x8*)&kb[i * 512 + lane * 8];
        vA[i] = *(const bf16x8*)&vb[i * 512 + lane * 8];
    }

    auto body = [&](int g, bf16x8* kuse, bf16x8* kload, bf16x8* vuse, bf16x8* vload) {
        const int gn = (g + 1) & 31;   // wrap: final prefetch re-reads g=0 (discarded)
#pragma unroll
        for (int i = 0; i < 4; ++i)
            kload[i] = *(const bf16x8*)&kb[gn * 2048 + i * 512 + lane * 8];
#pragma unroll
        for (int i = 0; i < 4; ++i)
            vload[i] = *(const bf16x8*)&vb[gn * 2048 + i * 512 + lane * 8];

        f32x4 s0[4], s1[4];
        __builtin_amdgcn_s_setprio(1);
#pragma unroll
        for (int qt = 0; qt < 4; ++qt) {
            f32x4 a = {};
            a = mfma32(kuse[0], qfr[qt][0], a);
            a = mfma32(kuse[1], qfr[qt][1], a);
            s0[qt] = a;
            f32x4 b = {};
            b = mfma32(kuse[2], qfr[qt][0], b);
            b = mfma32(kuse[3], qfr[qt][1], b);
            s1[qt] = b;
        }
        __builtin_amdgcn_s_setprio(0);

        bf16x8 pf[4];
#pragma unroll
        for (int qt = 0; qt < 4; ++qt) {
            float e0[4], e1[4];
#pragma unroll
            for (int r = 0; r < 4; ++r) {
                e0[r] = __builtin_amdgcn_exp2f(s0[qt][r]);
                e1[r] = __builtin_amdgcn_exp2f(s1[qt][r]);
            }
            lv[qt] += ((e0[0] + e0[1]) + (e0[2] + e0[3])) +
                      ((e1[0] + e1[1]) + (e1[2] + e1[3]));
            bf16x8 pb;
#pragma unroll
            for (int r = 0; r < 4; ++r) {
                pb[r]     = (__bf16)e0[r];
                pb[4 + r] = (__bf16)e1[r];
            }
            pf[qt] = pb;
        }

        __builtin_amdgcn_s_setprio(1);
#pragma unroll
        for (int dt = 0; dt < 4; ++dt)
#pragma unroll
            for (int qt = 0; qt < 4; ++qt)
                oacc[dt][qt] = mfma32(vuse[dt], pf[qt], oacc[dt][qt]);
        __builtin_amdgcn_s_setprio(0);
    };

    for (int it = 0; it < 16; ++it) {
        body(it * 2 + 0, kA, kB, vA, vB);
        body(it * 2 + 1, kB, kA, vB, vA);
    }

    // l: reduce lv over the 4 quads (keys are distributed quad-wise)
#pragma unroll
    for (int qt = 0; qt < 4; ++qt) {
        float L = lv[qt];
        L += __shfl_xor(L, 16, 64);
        L += __shfl_xor(L, 32, 64);
        if (quad == 0) sml[w][qt * 16 + l16] = L;
    }
#pragma unroll
    for (int qt = 0; qt < 4; ++qt) {
        const int q = qt * 16 + l16;
#pragma unroll
        for (int dt = 0; dt < 4; ++dt)
            *(f32x4*)&ldsO[w][q][dt * 16 + quad * 4] = oacc[dt][qt];
    }
    __syncthreads();
#pragma unroll
    for (int pass = 0; pass < 2; ++pass) {
        const int idx = pass * 256 + tid;
        const int q = idx >> 3, dseg = (idx & 7) * 8;
        const float L = sml[0][q] + sml[1][q] + sml[2][q] + sml[3][q];
        const float inv = 1.f / L;
        unsigned short o8[8];
#pragma unroll
        for (int i = 0; i < 8; ++i) {
            const float v = ldsO[0][q][dseg + i] + ldsO[1][q][dseg + i] +
                            ldsO[2][q][dseg + i] + ldsO[3][q][dseg + i];
            o8[i] = bfbits(v * inv);
        }
        *(uint4*)&attn_out[(size_t)(qb * 64 + q) * CDIM + h * DHEAD + dseg] = *(uint4*)o8;
    }
}

// ---------------- proj GEMM: 64x64 tiles (512 blocks = 2/CU), bf16-in, prefetch ------------
__global__ __launch_bounds__(256) void gemm_proj(
    const unsigned short* __restrict__ A,   // attn [4096][512] bf16
    const unsigned short* __restrict__ Bm,  // Wproj bf16 [512][512]
    const float* __restrict__ bias,
    float* __restrict__ c_out)              // [4096][512] fp32
{
    __shared__ __align__(16) unsigned short smem[2 * 64 * LDS_K];  // 10240 B
    unsigned short* lA = smem;
    unsigned short* lB = smem + 64 * LDS_K;

    const int tid = threadIdx.x;
    const int mBase = blockIdx.y * 64, nBase = blockIdx.x * 64;
    const int lane = tid & 63;
    const int w = __builtin_amdgcn_readfirstlane(tid >> 6);
    const int l16 = lane & 15, quad = lane >> 4;
    const int srow = tid >> 2, scol = (tid & 3) * 8;

    const unsigned short* pA = &A[(size_t)(mBase + srow) * CDIM + scol];
    const unsigned short* pB = &Bm[(size_t)(nBase + srow) * CDIM + scol];

    f32x4 acc[4] = {};   // wave w owns cols [w*16, w*16+16), all 64 rows

    uint4 rA, rB;
    auto issue = [&](int kt) {
        rA = *(const uint4*)(pA + kt);
        rB = *(const uint4*)(pB + kt);
    };
    issue(0);

    for (int kt = 0; kt < CDIM; kt += 32) {
        __syncthreads();
        *(uint4*)&lA[srow * LDS_K + scol] = rA;
        *(uint4*)&lB[srow * LDS_K + scol] = rB;
        __syncthreads();
        if (kt + 32 < CDIM) issue(kt + 32);

        bf16x8 af[4], bfr;
#pragma unroll
        for (int i = 0; i < 4; ++i)
            af[i] = *(const bf16x8*)&lA[(i * 16 + l16) * LDS_K + quad * 8];
        bfr = *(const bf16x8*)&lB[(w * 16 + l16) * LDS_K + quad * 8];
#pragma unroll
        for (int i = 0; i < 4; ++i)
            acc[i] = mfma32(af[i], bfr, acc[i]);
    }

#pragma unroll
    for (int i = 0; i < 4; ++i)
#pragma unroll
        for (int r = 0; r < 4; ++r) {
            const int grow = mBase + i * 16 + quad * 4 + r;
            const int gcol = nBase + w * 16 + l16;
            c_out[(size_t)grow * CDIM + gcol] = acc[i][r] + bias[gcol];
        }
}

extern "C" void kernel_launch(void* const* d_in, const int* in_sizes, int n_in,
                              void* d_out, int out_size, void* d_ws, size_t ws_size,
                              hipStream_t stream) {
    const float* x       = (const float*)d_in[0];
    const float* scale_p = (const float*)d_in[3];
    const float* Wqkv    = (const float*)d_in[4];
    const float* bqkv    = (const float*)d_in[5];
    const float* Wproj   = (const float*)d_in[6];
    const float* bproj   = (const float*)d_in[7];
    float* out = (float*)d_out;

    char* ws = (char*)d_ws;
    const size_t OFF_QKV  = 0;                        // 3*8*PHEAD bf16 = 12 MB
    const size_t OFF_ATTN = 12582912;                 // 4096*512 bf16  =  4 MB
    const size_t OFF_XB   = 16777216;                 // x bf16          =  4 MB
    const size_t OFF_WQB  = 20971520;                 // Wqkv bf16       = 1.5 MB
    const size_t OFF_WPB  = 22544384;                 // Wproj bf16      = 0.5 MB
    const size_t NEEDED   = OFF_WPB + 524288;         // 23 MB
    if (ws_size < NEEDED) return;

    unsigned short* qkvb  = (unsigned short*)(ws + OFF_QKV);
    unsigned short* attnb = (unsigned short*)(ws + OFF_ATTN);
    unsigned short* xb    = (unsigned short*)(ws + OFF_XB);
    unsigned short* wqb   = (unsigned short*)(ws + OFF_WQB);
    unsigned short* wpb   = (unsigned short*)(ws + OFF_WPB);

    cast3_k<<<1536, 256, 0, stream>>>(x, Wqkv, Wproj, xb, wqb, wpb);

    gemm_qkv<<<dim3(12, 64), 256, 0, stream>>>(xb, wqb, bqkv, scale_p, qkvb);

    const unsigned short* qfr = qkvb;
    const unsigned short* kfr = qkvb + (size_t)PHEAD * HEADS;
    const unsigned short* vfr = qkvb + (size_t)2 * PHEAD * HEADS;
    flash8_k<<<dim3(8, 64), 256, 0, stream>>>(qfr, kfr, vfr, attnb);

    gemm_proj<<<dim3(8, 64), 256, 0, stream>>>(attnb, wpb, bproj, out);
}